// Round 10
// baseline (167.874 us; speedup 1.0000x reference)
//
#include <hip/hip_runtime.h>
#include <hip/hip_bf16.h>
#include <cstddef>
#include <cstdint>

// LSTMCell fused: z = [u|h] @ [W|U]^T + bW + bE ; gates ; c/h update.
// fp32 in / fp32 out; bf16 MFMA internal, fp32 accum.
// R10: occupancy-driven redesign. R9 lesson: 256 regs/wave (acc128) caps at
//   2 waves/SIMD — LDS wasn't the limiter. Now wave tile 64r x 64gc -> acc=64,
//   W single-set direct->VGPR (32) via frag-interleaved Wbf3[hcol][k/8][g][8]
//   (one base ptr + imm offsets), A-only LDS dbuf 32 KB. Total ~126 regs
//   => 4 waves/SIMD = TWO independent 8-wave blocks/CU (m114 overlap).
//   BM=128 x BH=64 (8 h-tiles -> X traffic back to R8 level), grid 1024,
//   bijective XCD swizzle -> 512 KB W slice L2-resident per XCD.
//   R5 2-barrier rhythm (R6/R7/R8 schedule variants all <= it).
// Pre-pass: X=[u|h]->bf16 (32MB), Wbf3 frag-interleaved (4MB), combined bias.

#define BDIM 16384
#define HDIM 512

typedef __attribute__((ext_vector_type(8))) short bf16x8;
typedef __attribute__((ext_vector_type(4))) float f32x4;

struct Params {
  const float* u;
  const float* h;
  const float* c;
  const float* W[4];
  const float* U[4];
  const float* bW[4];
  const float* bE[4];
  float* outh;
  float* outc;
};

__device__ __forceinline__ float sigmoidf_(float x) {
  return 1.0f / (1.0f + __expf(-x));
}
__device__ __forceinline__ float tanhf_(float x) {
  return 2.0f / (1.0f + __expf(-2.0f * x)) - 1.0f;
}

__device__ __forceinline__ void async16(const void* g, void* l) {
  __builtin_amdgcn_global_load_lds((const __attribute__((address_space(1))) void*)g,
                                   (__attribute__((address_space(3))) void*)l,
                                   16, 0, 0);
}

__device__ __forceinline__ bf16x8 cvt8(f32x4 a, f32x4 b) {
  bf16x8 r;
#pragma unroll
  for (int j = 0; j < 4; ++j) {
    __hip_bfloat16 t = __float2bfloat16(a[j]);
    r[j] = *reinterpret_cast<short*>(&t);
  }
#pragma unroll
  for (int j = 0; j < 4; ++j) {
    __hip_bfloat16 t = __float2bfloat16(b[j]);
    r[4 + j] = *reinterpret_cast<short*>(&t);
  }
  return r;
}

// ---------- pre-pass 1: X = [u|h] -> bf16 [16384][1024] ----------
__global__ void cvt_x_kernel(const float* __restrict__ u, const float* __restrict__ h,
                             __hip_bfloat16* __restrict__ Xbf) {
  const size_t e = ((size_t)blockIdx.x * 512 + threadIdx.x) * 8;
  const int r = (int)(e >> 10);
  const int cidx = (int)(e & 1023);
  const float* s = (cidx < 512) ? (u + (size_t)r * 512 + cidx)
                                : (h + (size_t)r * 512 + (cidx - 512));
  f32x4 v0 = *(const f32x4*)s;
  f32x4 v1 = *(const f32x4*)(s + 4);
  *(bf16x8*)(Xbf + e) = cvt8(v0, v1);
}

// ---------- pre-pass 2: Wbf3[hcol][k/8][gate][8] bf16 + combined bias ----
// element (hcol, k, g) at ((hcol*128 + k/8)*4 + g)*8 + k%8
// thread gt handles out elems gt*8..gt*8+7: g=gt&3, j=(gt>>2)&127, hcol=gt>>9
__global__ void cvt_w_kernel(Params p, __hip_bfloat16* __restrict__ Wbf3,
                             float* __restrict__ biasC) {
  const size_t gt = (size_t)blockIdx.x * 512 + threadIdx.x;
  const int g = (int)(gt & 3);
  const int j = (int)((gt >> 2) & 127);
  const int hcol = (int)(gt >> 9);
  const int k0 = j * 8;
  const float* s = (k0 < 512) ? (p.W[g] + (size_t)hcol * 512 + k0)
                              : (p.U[g] + (size_t)hcol * 512 + (k0 - 512));
  f32x4 v0 = *(const f32x4*)s;
  f32x4 v1 = *(const f32x4*)(s + 4);
  *(bf16x8*)(Wbf3 + gt * 8) = cvt8(v0, v1);
  if (gt < 2048) {
    const int bg = (int)(gt >> 9), hh = (int)(gt & 511);
    biasC[gt] = p.bW[bg][hh] + p.bE[bg][hh];
  }
}

// ---------- main GEMM + fused gates ----------
__launch_bounds__(512, 4)
__global__ void lstm_main_kernel(const __hip_bfloat16* __restrict__ Xbf,
                                 const __hip_bfloat16* __restrict__ Wbf3,
                                 const float* __restrict__ biasC,
                                 const float* __restrict__ c,
                                 float* __restrict__ outh,
                                 float* __restrict__ outc) {
  // LDS: A only, 2 bufs x [128][64] bf16 = 32 KB  (2 blocks/CU resident)
  __shared__ char smem[32768];

  const int tid = threadIdx.x;
  const int w   = tid >> 6;   // 0..7
  const int l   = tid & 63;
  const int wm  = w >> 2;     // 0..1 : 64-row half
  const int wh  = w & 3;      // 0..3 : 16-hcol group

  // XCD swizzle: 1024 blocks, 8 XCDs -> XCD x owns h_tile x (512KB L2 slice)
  const int swz = (blockIdx.x & 7) * 128 + (blockIdx.x >> 3);
  const int m_tile = swz & 127;
  const int h_tile = swz >> 7;
  const int rowA0 = m_tile * 128;
  const int nrow0 = h_tile * 64;

  const int rsub = l >> 3;             // 0..7 row-within-8
  const int slot = (l & 7) ^ rsub;     // pre-swizzled source 16B slot

  // A staging: wave w stages rows w*16 + {0,8} + rsub; LDS dest linear.
  const __hip_bfloat16* gpA =
      Xbf + (size_t)(rowA0 + w * 16 + rsub) * 1024 + slot * 8;
  const int dbase = (w * 16) * 128 + (l & 7) * 16 + rsub * 128;

  // W frag base: hcol = nrow0 + wh*16 + (l&15); j-slot = l>>4.
  // frag(t, kk, g) at wpB + t*256 + kk*128 + g*8 elems (imm-foldable offsets)
  const __hip_bfloat16* wpB =
      Wbf3 + ((size_t)(nrow0 + wh * 16 + (l & 15)) * 128 + (l >> 4)) * 32;

  f32x4 acc[4][4] = {};  // [gate][m-frag]  = 64 AGPRs
  bf16x8 wv[8];          // W frags [g][kk] = 32 VGPRs

  auto STAGE = [&](int t, char* buf) {
    async16(gpA + t * 64, buf + dbase);
    async16(gpA + (size_t)8 * 1024 + t * 64, buf + dbase + 8 * 128);
  };
  auto LOADW = [&](int t) {
#pragma unroll
    for (int g = 0; g < 4; ++g) {
      wv[g * 2]     = *(const bf16x8*)(wpB + t * 256 + g * 8);
      wv[g * 2 + 1] = *(const bf16x8*)(wpB + t * 256 + 128 + g * 8);
    }
  };

  const int xr  = (l & 7) << 4;   // read-side LDS swizzle
  const int ar  = l & 15;
  const int kof = (l >> 4) * 16;

  auto COMPUTE = [&](const char* buf) {
#pragma unroll
    for (int kk = 0; kk < 2; ++kk) {
      const int kb = (kk * 64 + kof) ^ xr;
      bf16x8 av[4];
#pragma unroll
      for (int mf = 0; mf < 4; ++mf)
        av[mf] = *(const bf16x8*)(buf + (wm * 64 + mf * 16 + ar) * 128 + kb);
#pragma unroll
      for (int g = 0; g < 4; ++g)
#pragma unroll
        for (int mf = 0; mf < 4; ++mf)
          acc[g][mf] = __builtin_amdgcn_mfma_f32_16x16x32_bf16(
              av[mf], wv[g * 2 + kk], acc[g][mf], 0, 0, 0);
    }
  };

  char* buf0 = smem;
  char* buf1 = smem + 16384;

  STAGE(0, buf0);
  LOADW(0);
  __syncthreads();  // vmcnt(0) drain + barrier

  for (int t = 0; t < 16; ++t) {
    char* buf  = (t & 1) ? buf1 : buf0;
    char* nbuf = (t & 1) ? buf0 : buf1;
    if (t < 15) STAGE(t + 1, nbuf);   // prefetch under MFMAs
    COMPUTE(buf);                      // uses wv(t)
    if (t < 15) LOADW(t + 1);          // WAR: after last wv(t) use
    __syncthreads();                   // drains stage + W loads
  }

  // ---- fused epilogue ----
  // C/D layout: col = lane&15, row = (lane>>4)*4 + reg   [m89/m91]
  const int lr = (l >> 4) * 4;
  const int lc = l & 15;
  const int hc = nrow0 + wh * 16 + lc;
  const float bzi = biasC[0 * 512 + hc];
  const float bzf = biasC[1 * 512 + hc];
  const float bzg = biasC[2 * 512 + hc];
  const float bzo = biasC[3 * 512 + hc];
#pragma unroll
  for (int mf = 0; mf < 4; ++mf) {
#pragma unroll
    for (int j = 0; j < 4; ++j) {
      const int row = rowA0 + wm * 64 + mf * 16 + lr + j;
      const float zi = acc[0][mf][j] + bzi;
      const float zf = acc[1][mf][j] + bzf;
      const float zg = acc[2][mf][j] + bzg;
      const float zo = acc[3][mf][j] + bzo;
      const float ig = sigmoidf_(zi);
      const float fg = sigmoidf_(zf);
      const float gg = tanhf_(zg);
      const float og = sigmoidf_(zo);
      const size_t idx = (size_t)row * 512 + hc;
      const float cv = c[idx];
      const float cn = fg * cv + ig * gg;
      const float hn = og * tanhf_(cn);
      outh[idx] = hn;
      outc[idx] = cn;
    }
  }
}

// ---------- fallback: proven R2 kernel ----------
__launch_bounds__(256, 2)
__global__ void lstm_legacy_kernel(Params p) {
  __shared__ char smem[32768];
  __shared__ float biasLDS[4][32];

  const int tid = threadIdx.x;
  const int w   = tid >> 6;
  const int l   = tid & 63;
  const int m_tile = blockIdx.x & 127;
  const int h_tile = blockIdx.x >> 7;

  char* smemA = smem;
  char* smemW = smem + 16384;
  const int rowA0 = m_tile * 128;
  const int nrow0 = h_tile * 32;

  if (tid < 128) {
    const int g = tid >> 5, hh = tid & 31;
    const int hcb = nrow0 + hh;
    biasLDS[g][hh] = p.bW[g][hcb] + p.bE[g][hcb];
  }

  const int sr = tid >> 3;
  const int sc = tid & 7;
  const int wcol = (sc * 16) ^ ((sr & 7) << 4);

  f32x4 acc[4][2][2] = {};
  f32x4 rg[16];

  auto load_tile = [&](int kt) {
    const float* sA = (kt < 8) ? p.u : p.h;
    const int kc = (kt & 7) * 64;
#pragma unroll
    for (int cc = 0; cc < 4; ++cc) {
      const float* gp = sA + (size_t)(rowA0 + cc * 32 + sr) * 512 + kc + sc * 8;
      rg[cc * 2]     = *(const f32x4*)gp;
      rg[cc * 2 + 1] = *(const f32x4*)(gp + 4);
    }
#pragma unroll
    for (int cc = 0; cc < 4; ++cc) {
      const float* sW = (kt < 8) ? p.W[cc] : p.U[cc];
      const float* gp = sW + (size_t)(nrow0 + sr) * 512 + kc + sc * 8;
      rg[8 + cc * 2]     = *(const f32x4*)gp;
      rg[8 + cc * 2 + 1] = *(const f32x4*)(gp + 4);
    }
  };

  auto write_tile = [&]() {
#pragma unroll
    for (int cc = 0; cc < 4; ++cc)
      *(bf16x8*)(smemA + (cc * 32 + sr) * 128 + wcol) = cvt8(rg[cc * 2], rg[cc * 2 + 1]);
#pragma unroll
    for (int cc = 0; cc < 4; ++cc)
      *(bf16x8*)(smemW + (cc * 32 + sr) * 128 + wcol) = cvt8(rg[8 + cc * 2], rg[8 + cc * 2 + 1]);
  };

  const int xr = (l & 7) << 4;

  auto compute = [&]() {
#pragma unroll
    for (int kk = 0; kk < 2; ++kk) {
      const int kb = (kk * 64 + (l >> 4) * 16) ^ xr;
      bf16x8 a0 = *(const bf16x8*)(smemA + (w * 32 +      (l & 15)) * 128 + kb);
      bf16x8 a1 = *(const bf16x8*)(smemA + (w * 32 + 16 + (l & 15)) * 128 + kb);
#pragma unroll
      for (int g = 0; g < 4; ++g) {
#pragma unroll
        for (int ni = 0; ni < 2; ++ni) {
          bf16x8 b = *(const bf16x8*)(smemW + (g * 32 + ni * 16 + (l & 15)) * 128 + kb);
          acc[g][0][ni] = __builtin_amdgcn_mfma_f32_16x16x32_bf16(a0, b, acc[g][0][ni], 0, 0, 0);
          acc[g][1][ni] = __builtin_amdgcn_mfma_f32_16x16x32_bf16(a1, b, acc[g][1][ni], 0, 0, 0);
        }
      }
    }
  };

  load_tile(0);
  for (int kt = 0; kt < 16; ++kt) {
    write_tile();
    __syncthreads();
    if (kt < 15) load_tile(kt + 1);
    compute();
    __syncthreads();
  }

  const int lr = (l >> 4) * 4;
  const int lc = l & 15;
#pragma unroll
  for (int mi = 0; mi < 2; ++mi) {
#pragma unroll
    for (int j = 0; j < 4; ++j) {
      const int row = rowA0 + w * 32 + mi * 16 + lr + j;
#pragma unroll
      for (int ni = 0; ni < 2; ++ni) {
        const int hcc = nrow0 + ni * 16 + lc;
        const int bcol = ni * 16 + lc;
        const float zi = acc[0][mi][ni][j] + biasLDS[0][bcol];
        const float zf = acc[1][mi][ni][j] + biasLDS[1][bcol];
        const float zg = acc[2][mi][ni][j] + biasLDS[2][bcol];
        const float zo = acc[3][mi][ni][j] + biasLDS[3][bcol];
        const float ig = sigmoidf_(zi);
        const float fg = sigmoidf_(zf);
        const float gg = tanhf_(zg);
        const float og = sigmoidf_(zo);
        const size_t idx = (size_t)row * 512 + hcc;
        const float cv = p.c[idx];
        const float cn = fg * cv + ig * gg;
        const float hn = og * tanhf_(cn);
        p.outh[idx] = hn;
        p.outc[idx] = cn;
      }
    }
  }
}

extern "C" void kernel_launch(void* const* d_in, const int* in_sizes, int n_in,
                              void* d_out, int out_size, void* d_ws, size_t ws_size,
                              hipStream_t stream) {
  Params p;
  p.u = (const float*)d_in[0];
  p.h = (const float*)d_in[1];
  p.c = (const float*)d_in[2];
  p.W[0] = (const float*)d_in[3];
  p.bW[0] = (const float*)d_in[4];
  p.W[1] = (const float*)d_in[5];
  p.bW[1] = (const float*)d_in[6];
  p.W[2] = (const float*)d_in[7];
  p.bW[2] = (const float*)d_in[8];
  p.W[3] = (const float*)d_in[9];
  p.bW[3] = (const float*)d_in[10];
  p.U[0] = (const float*)d_in[11];
  p.U[1] = (const float*)d_in[12];
  p.U[2] = (const float*)d_in[13];
  p.U[3] = (const float*)d_in[14];
  p.bE[0] = (const float*)d_in[15];
  p.bE[1] = (const float*)d_in[16];
  p.bE[2] = (const float*)d_in[17];
  p.bE[3] = (const float*)d_in[18];
  p.outh = (float*)d_out;
  p.outc = (float*)d_out + (size_t)BDIM * HDIM;

  const size_t X_BYTES = (size_t)BDIM * 1024 * 2;        // 32 MB
  const size_t W_BYTES = (size_t)4 * 512 * 1024 * 2;     // 4 MB
  const size_t B_BYTES = 2048 * 4;                       // 8 KB
  if (ws_size >= X_BYTES + W_BYTES + B_BYTES) {
    __hip_bfloat16* Xbf = (__hip_bfloat16*)d_ws;
    __hip_bfloat16* Wbf3 = (__hip_bfloat16*)((char*)d_ws + X_BYTES);
    float* biasC = (float*)((char*)d_ws + X_BYTES + W_BYTES);

    hipLaunchKernelGGL(cvt_x_kernel, dim3(4096), dim3(512), 0, stream, p.u, p.h, Xbf);
    hipLaunchKernelGGL(cvt_w_kernel, dim3(512), dim3(512), 0, stream, p, Wbf3, biasC);
    hipLaunchKernelGGL(lstm_main_kernel, dim3(1024), dim3(512), 0, stream,
                       Xbf, Wbf3, biasC, p.c, p.outh, p.outc);
  } else {
    hipLaunchKernelGGL(lstm_legacy_kernel, dim3(2048), dim3(256), 0, stream, p);
  }
}

// Round 11
// 107.954 us; speedup vs baseline: 1.5551x; 1.5551x over previous
//
#include <hip/hip_runtime.h>
#include <hip/hip_bf16.h>
#include <cstddef>
#include <cstdint>

// LSTMCell fused: z = [u|h] @ [W|U]^T + bW + bE ; gates ; c/h update.
// fp32 in / fp32 out; bf16 MFMA internal, fp32 accum.
// R11: faithful m201 8-phase port on the proven 256x256eff geometry.
//   8 waves (2 wm x 4 wh), BK=64, LDS 2 slots x (A 32KB + B 32KB) = 128 KB.
//   Per K-tile, 4 phases (quadrant = m-half x gate-half), each:
//   {ds_read subtile; stage 1 half-tile for t+1/t+2 into the region killed
//    one phase earlier; [lgkmcnt(8) hint]; s_barrier; lgkmcnt(0)+fence;
//    setprio(1); 16 MFMA; setprio(0); s_barrier}.
//   vmcnt(6) ONCE per tile at ph4 (3 half-tiles stay in flight across
//   barriers); t==14 uses vmcnt(0) (tail: only A(h1,15) outstanding).
//   Dead-region proof: A halves split by row bit6 (h*64..h*64+63 within each
//   wm 128-row block) so wave wm's mh-phase reads exactly region h; B halves
//   by gate pair {0,1}/{2,3}. Stage(ph2..4 -> slot t&1 regions read at
//   ph1/ph1/ph2 of THIS tile; ph1 -> slot (t+1)&1 A(h1) read at ph3(t-1)).
//   R10 lesson: occupancy was not the limiter; per-tile overhead was.
// Pre-pass: X=[u|h]->bf16 (32MB), W gate-major bf16 (4MB), combined bias.

#define BDIM 16384
#define HDIM 512

typedef __attribute__((ext_vector_type(8))) short bf16x8;
typedef __attribute__((ext_vector_type(4))) float f32x4;

struct Params {
  const float* u;
  const float* h;
  const float* c;
  const float* W[4];
  const float* U[4];
  const float* bW[4];
  const float* bE[4];
  float* outh;
  float* outc;
};

__device__ __forceinline__ float sigmoidf_(float x) {
  return 1.0f / (1.0f + __expf(-x));
}
__device__ __forceinline__ float tanhf_(float x) {
  return 2.0f / (1.0f + __expf(-2.0f * x)) - 1.0f;
}

__device__ __forceinline__ void async16(const void* g, void* l) {
  __builtin_amdgcn_global_load_lds((const __attribute__((address_space(1))) void*)g,
                                   (__attribute__((address_space(3))) void*)l,
                                   16, 0, 0);
}

__device__ __forceinline__ bf16x8 cvt8(f32x4 a, f32x4 b) {
  bf16x8 r;
#pragma unroll
  for (int j = 0; j < 4; ++j) {
    __hip_bfloat16 t = __float2bfloat16(a[j]);
    r[j] = *reinterpret_cast<short*>(&t);
  }
#pragma unroll
  for (int j = 0; j < 4; ++j) {
    __hip_bfloat16 t = __float2bfloat16(b[j]);
    r[4 + j] = *reinterpret_cast<short*>(&t);
  }
  return r;
}

// ---------- pre-pass 1: X = [u|h] -> bf16 [16384][1024] ----------
__global__ void cvt_x_kernel(const float* __restrict__ u, const float* __restrict__ h,
                             __hip_bfloat16* __restrict__ Xbf) {
  const size_t e = ((size_t)blockIdx.x * 512 + threadIdx.x) * 8;
  const int r = (int)(e >> 10);
  const int cidx = (int)(e & 1023);
  const float* s = (cidx < 512) ? (u + (size_t)r * 512 + cidx)
                                : (h + (size_t)r * 512 + (cidx - 512));
  f32x4 v0 = *(const f32x4*)s;
  f32x4 v1 = *(const f32x4*)(s + 4);
  *(bf16x8*)(Xbf + e) = cvt8(v0, v1);
}

// ---------- pre-pass 2: Wbf[g][hcol][k'] bf16 + combined bias ----------
__global__ void cvt_w_kernel(Params p, __hip_bfloat16* __restrict__ Wbf,
                             float* __restrict__ biasC) {
  const size_t gt = (size_t)blockIdx.x * 512 + threadIdx.x;
  const size_t e = gt * 8;
  const int g = (int)(e >> 19);
  const int rem = (int)(e & 524287);
  const int hcol = rem >> 10;
  const int k = rem & 1023;
  const float* s = (k < 512) ? (p.W[g] + (size_t)hcol * 512 + k)
                             : (p.U[g] + (size_t)hcol * 512 + (k - 512));
  f32x4 v0 = *(const f32x4*)s;
  f32x4 v1 = *(const f32x4*)(s + 4);
  *(bf16x8*)(Wbf + e) = cvt8(v0, v1);
  if (gt < 2048) {
    const int bg = (int)(gt >> 9), hh = (int)(gt & 511);
    biasC[gt] = p.bW[bg][hh] + p.bE[bg][hh];
  }
}

// ---------- main GEMM + fused gates: 8-phase template ----------
#define VM6 asm volatile("s_waitcnt vmcnt(6)" ::: "memory")
#define VM0 asm volatile("s_waitcnt vmcnt(0)" ::: "memory")
#define LG0 asm volatile("s_waitcnt lgkmcnt(0)" ::: "memory")
#define LG8 asm volatile("s_waitcnt lgkmcnt(8)" ::: "memory")
#define FENCE __builtin_amdgcn_sched_barrier(0)
#define BAR                                  \
  do {                                       \
    asm volatile("" ::: "memory");           \
    __builtin_amdgcn_s_barrier();            \
    asm volatile("" ::: "memory");           \
  } while (0)

__launch_bounds__(512, 2)
__global__ void lstm_main_kernel(const __hip_bfloat16* __restrict__ Xbf,
                                 const __hip_bfloat16* __restrict__ Wbf,
                                 const float* __restrict__ biasC,
                                 const float* __restrict__ c,
                                 float* __restrict__ outh,
                                 float* __restrict__ outc) {
  // slot s at s*64KB: A [256][128B] + B [256][128B]
  __shared__ char smem[131072];

  const int tid = threadIdx.x;
  const int w   = tid >> 6;   // 0..7
  const int l   = tid & 63;
  const int wm  = w >> 2;     // 0..1 : 128-row half
  const int wh  = w & 3;      // 0..3 : 16-hcol group

  // XCD swizzle: 512 blocks, 8 XCDs -> XCD x owns h_tile x (512KB L2 slice)
  const int swz = (blockIdx.x & 7) * 64 + (blockIdx.x >> 3);
  const int m_tile = swz & 63;
  const int h_tile = swz >> 6;
  const int rowA0 = m_tile * 256;
  const int nrow0 = h_tile * 64;

  const int trow = tid >> 3;               // 0..63
  const int rsub = trow & 7;
  const int slot8 = ((tid & 7) ^ rsub) * 8;  // pre-swizzled source 16B slot
  const int dofs = trow * 128 + (tid & 7) * 16;

  // staging source bases (advance t*64 elems = 128 B per K-tile)
  const __hip_bfloat16* srcA = Xbf + (size_t)(rowA0 + trow) * 1024 + slot8;
  const __hip_bfloat16* srcW = Wbf + (size_t)(nrow0 + trow) * 1024 + slot8;

  f32x4 acc[4][8] = {};  // [gate][m-frag]

  const int xr  = (l & 7) << 4;
  const int ar  = l & 15;
  const int kb0 = ((l >> 4) * 16) ^ xr;
  const int kb1 = (64 + (l >> 4) * 16) ^ xr;

  // stage A half h of tile t (rows j*128 + h*64 + trow, j=0,1)
  auto ST_A = [&](int t, int h) {
    char* d = smem + ((t & 1) << 16) + h * 64 * 128 + dofs;
    const __hip_bfloat16* s = srcA + (size_t)(h * 64) * 1024 + t * 64;
    async16(s, d);
    async16(s + (size_t)128 * 1024, d + 128 * 128);
  };
  // stage B gate-half G of tile t (gates 2G+j, j=0,1)
  auto ST_B = [&](int t, int G) {
    char* d = smem + ((t & 1) << 16) + 32768 + G * 128 * 128 + dofs;
    const __hip_bfloat16* s = srcW + (size_t)(G * 2 * 512) * 1024 + t * 64;
    async16(s, d);
    async16(s + (size_t)512 * 1024, d + 64 * 128);
  };
  auto RD_A = [&](const char* sA, int mh, bf16x8* d) {
#pragma unroll
    for (int mf = 0; mf < 4; ++mf) {
      const char* p = sA + (wm * 128 + mh * 64 + mf * 16 + ar) * 128;
      d[mf * 2 + 0] = *(const bf16x8*)(p + kb0);
      d[mf * 2 + 1] = *(const bf16x8*)(p + kb1);
    }
  };
  auto RD_B = [&](const char* sB, int G, bf16x8* d) {
#pragma unroll
    for (int g2 = 0; g2 < 2; ++g2) {
      const char* p = sB + ((G * 2 + g2) * 64 + wh * 16 + ar) * 128;
      d[g2 * 2 + 0] = *(const bf16x8*)(p + kb0);
      d[g2 * 2 + 1] = *(const bf16x8*)(p + kb1);
    }
  };
  auto MM = [&](int mh, int G, const bf16x8* a, const bf16x8* b) {
    __builtin_amdgcn_s_setprio(1);
#pragma unroll
    for (int g2 = 0; g2 < 2; ++g2)
#pragma unroll
      for (int mf = 0; mf < 4; ++mf)
#pragma unroll
        for (int kk = 0; kk < 2; ++kk)
          acc[G * 2 + g2][mh * 4 + mf] = __builtin_amdgcn_mfma_f32_16x16x32_bf16(
              a[mf * 2 + kk], b[g2 * 2 + kk], acc[G * 2 + g2][mh * 4 + mf], 0, 0, 0);
    __builtin_amdgcn_s_setprio(0);
  };

  // prologue: tile0 all 4 halves + tile1 {A(h0), B(G0), B(G1)} in issue order
  ST_A(0, 0); ST_B(0, 0); ST_B(0, 1); ST_A(0, 1);
  ST_A(1, 0); ST_B(1, 0); ST_B(1, 1);
  VM6; FENCE;   // tile0 complete; tile1's 3 halves stay in flight
  BAR;

  bf16x8 aF[8], b0[4], b1[4];

  for (int t = 0; t < 16; ++t) {
    const char* sA = smem + ((t & 1) << 16);
    const char* sB = sA + 32768;

    // ---- ph1: (m0,G0). reads 12; stage A(h1, t+1) ----
    RD_A(sA, 0, aF);
    RD_B(sB, 0, b0);
    if (t + 1 < 16) ST_A(t + 1, 1);
    LG8;
    BAR;
    LG0; FENCE;
    MM(0, 0, aF, b0);
    BAR;

    // ---- ph2: (m0,G1). reads 4; stage A(h0, t+2) ----
    RD_B(sB, 1, b1);
    if (t + 2 < 16) ST_A(t + 2, 0);
    BAR;
    LG0; FENCE;
    MM(0, 1, aF, b1);
    BAR;

    // ---- ph3: (m1,G0). reads 8; stage B(G0, t+2) ----
    RD_A(sA, 1, aF);
    if (t + 2 < 16) ST_B(t + 2, 0);
    BAR;
    LG0; FENCE;
    MM(1, 0, aF, b0);
    BAR;

    // ---- ph4: (m1,G1). no reads; stage B(G1, t+2); counted vmcnt ----
    if (t + 2 < 16) ST_B(t + 2, 1);
    MM(1, 1, aF, b1);
    if (t == 14) { VM0; } else { VM6; }
    FENCE;
    BAR;
  }

  // ---- fused epilogue ----
  // C/D layout: col = lane&15, row = (lane>>4)*4 + reg   [m89/m91]
  const int lr = (l >> 4) * 4;
  const int lc = l & 15;
  const int hc = nrow0 + wh * 16 + lc;
  const float bzi = biasC[0 * 512 + hc];
  const float bzf = biasC[1 * 512 + hc];
  const float bzg = biasC[2 * 512 + hc];
  const float bzo = biasC[3 * 512 + hc];
#pragma unroll
  for (int mf = 0; mf < 8; ++mf) {
#pragma unroll
    for (int j = 0; j < 4; ++j) {
      const int row = rowA0 + wm * 128 + mf * 16 + lr + j;
      const float zi = acc[0][mf][j] + bzi;
      const float zf = acc[1][mf][j] + bzf;
      const float zg = acc[2][mf][j] + bzg;
      const float zo = acc[3][mf][j] + bzo;
      const float ig = sigmoidf_(zi);
      const float fg = sigmoidf_(zf);
      const float gg = tanhf_(zg);
      const float og = sigmoidf_(zo);
      const size_t idx = (size_t)row * 512 + hc;
      const float cv = c[idx];
      const float cn = fg * cv + ig * gg;
      const float hn = og * tanhf_(cn);
      outh[idx] = hn;
      outc[idx] = cn;
    }
  }
}

// ---------- fallback: proven R2 kernel ----------
__launch_bounds__(256, 2)
__global__ void lstm_legacy_kernel(Params p) {
  __shared__ char smem[32768];
  __shared__ float biasLDS[4][32];

  const int tid = threadIdx.x;
  const int w   = tid >> 6;
  const int l   = tid & 63;
  const int m_tile = blockIdx.x & 127;
  const int h_tile = blockIdx.x >> 7;

  char* smemA = smem;
  char* smemW = smem + 16384;
  const int rowA0 = m_tile * 128;
  const int nrow0 = h_tile * 32;

  if (tid < 128) {
    const int g = tid >> 5, hh = tid & 31;
    const int hcb = nrow0 + hh;
    biasLDS[g][hh] = p.bW[g][hcb] + p.bE[g][hcb];
  }

  const int sr = tid >> 3;
  const int sc = tid & 7;
  const int wcol = (sc * 16) ^ ((sr & 7) << 4);

  f32x4 acc[4][2][2] = {};
  f32x4 rg[16];

  auto load_tile = [&](int kt) {
    const float* sA = (kt < 8) ? p.u : p.h;
    const int kc = (kt & 7) * 64;
#pragma unroll
    for (int cc = 0; cc < 4; ++cc) {
      const float* gp = sA + (size_t)(rowA0 + cc * 32 + sr) * 512 + kc + sc * 8;
      rg[cc * 2]     = *(const f32x4*)gp;
      rg[cc * 2 + 1] = *(const f32x4*)(gp + 4);
    }
#pragma unroll
    for (int cc = 0; cc < 4; ++cc) {
      const float* sW = (kt < 8) ? p.W[cc] : p.U[cc];
      const float* gp = sW + (size_t)(nrow0 + sr) * 512 + kc + sc * 8;
      rg[8 + cc * 2]     = *(const f32x4*)gp;
      rg[8 + cc * 2 + 1] = *(const f32x4*)(gp + 4);
    }
  };

  auto write_tile = [&]() {
#pragma unroll
    for (int cc = 0; cc < 4; ++cc)
      *(bf16x8*)(smemA + (cc * 32 + sr) * 128 + wcol) = cvt8(rg[cc * 2], rg[cc * 2 + 1]);
#pragma unroll
    for (int cc = 0; cc < 4; ++cc)
      *(bf16x8*)(smemW + (cc * 32 + sr) * 128 + wcol) = cvt8(rg[8 + cc * 2], rg[8 + cc * 2 + 1]);
  };

  const int xr = (l & 7) << 4;

  auto compute = [&]() {
#pragma unroll
    for (int kk = 0; kk < 2; ++kk) {
      const int kb = (kk * 64 + (l >> 4) * 16) ^ xr;
      bf16x8 a0 = *(const bf16x8*)(smemA + (w * 32 +      (l & 15)) * 128 + kb);
      bf16x8 a1 = *(const bf16x8*)(smemA + (w * 32 + 16 + (l & 15)) * 128 + kb);
#pragma unroll
      for (int g = 0; g < 4; ++g) {
#pragma unroll
        for (int ni = 0; ni < 2; ++ni) {
          bf16x8 b = *(const bf16x8*)(smemW + (g * 32 + ni * 16 + (l & 15)) * 128 + kb);
          acc[g][0][ni] = __builtin_amdgcn_mfma_f32_16x16x32_bf16(a0, b, acc[g][0][ni], 0, 0, 0);
          acc[g][1][ni] = __builtin_amdgcn_mfma_f32_16x16x32_bf16(a1, b, acc[g][1][ni], 0, 0, 0);
        }
      }
    }
  };

  load_tile(0);
  for (int kt = 0; kt < 16; ++kt) {
    write_tile();
    __syncthreads();
    if (kt < 15) load_tile(kt + 1);
    compute();
    __syncthreads();
  }

  const int lr = (l >> 4) * 4;
  const int lc = l & 15;
#pragma unroll
  for (int mi = 0; mi < 2; ++mi) {
#pragma unroll
    for (int j = 0; j < 4; ++j) {
      const int row = rowA0 + w * 32 + mi * 16 + lr + j;
#pragma unroll
      for (int ni = 0; ni < 2; ++ni) {
        const int hcc = nrow0 + ni * 16 + lc;
        const int bcol = ni * 16 + lc;
        const float zi = acc[0][mi][ni][j] + biasLDS[0][bcol];
        const float zf = acc[1][mi][ni][j] + biasLDS[1][bcol];
        const float zg = acc[2][mi][ni][j] + biasLDS[2][bcol];
        const float zo = acc[3][mi][ni][j] + biasLDS[3][bcol];
        const float ig = sigmoidf_(zi);
        const float fg = sigmoidf_(zf);
        const float gg = tanhf_(zg);
        const float og = sigmoidf_(zo);
        const size_t idx = (size_t)row * 512 + hcc;
        const float cv = p.c[idx];
        const float cn = fg * cv + ig * gg;
        const float hn = og * tanhf_(cn);
        p.outh[idx] = hn;
        p.outc[idx] = cn;
      }
    }
  }
}

extern "C" void kernel_launch(void* const* d_in, const int* in_sizes, int n_in,
                              void* d_out, int out_size, void* d_ws, size_t ws_size,
                              hipStream_t stream) {
  Params p;
  p.u = (const float*)d_in[0];
  p.h = (const float*)d_in[1];
  p.c = (const float*)d_in[2];
  p.W[0] = (const float*)d_in[3];
  p.bW[0] = (const float*)d_in[4];
  p.W[1] = (const float*)d_in[5];
  p.bW[1] = (const float*)d_in[6];
  p.W[2] = (const float*)d_in[7];
  p.bW[2] = (const float*)d_in[8];
  p.W[3] = (const float*)d_in[9];
  p.bW[3] = (const float*)d_in[10];
  p.U[0] = (const float*)d_in[11];
  p.U[1] = (const float*)d_in[12];
  p.U[2] = (const float*)d_in[13];
  p.U[3] = (const float*)d_in[14];
  p.bE[0] = (const float*)d_in[15];
  p.bE[1] = (const float*)d_in[16];
  p.bE[2] = (const float*)d_in[17];
  p.bE[3] = (const float*)d_in[18];
  p.outh = (float*)d_out;
  p.outc = (float*)d_out + (size_t)BDIM * HDIM;

  const size_t X_BYTES = (size_t)BDIM * 1024 * 2;        // 32 MB
  const size_t W_BYTES = (size_t)4 * 512 * 1024 * 2;     // 4 MB
  const size_t B_BYTES = 2048 * 4;                       // 8 KB
  if (ws_size >= X_BYTES + W_BYTES + B_BYTES) {
    __hip_bfloat16* Xbf = (__hip_bfloat16*)d_ws;
    __hip_bfloat16* Wbf = (__hip_bfloat16*)((char*)d_ws + X_BYTES);
    float* biasC = (float*)((char*)d_ws + X_BYTES + W_BYTES);

    hipLaunchKernelGGL(cvt_x_kernel, dim3(4096), dim3(512), 0, stream, p.u, p.h, Xbf);
    hipLaunchKernelGGL(cvt_w_kernel, dim3(512), dim3(512), 0, stream, p, Wbf, biasC);
    hipLaunchKernelGGL(lstm_main_kernel, dim3(512), dim3(512), 0, stream,
                       Xbf, Wbf, biasC, p.c, p.outh, p.outc);
  } else {
    hipLaunchKernelGGL(lstm_legacy_kernel, dim3(2048), dim3(256), 0, stream, p);
  }
}